// Round 6
// baseline (81.881 us; speedup 1.0000x reference)
//
#include <hip/hip_runtime.h>
#include <hip/hip_bf16.h>

typedef __attribute__((ext_vector_type(8))) short bf16x8;
typedef __attribute__((ext_vector_type(4))) float f32x4;
typedef __attribute__((ext_vector_type(4))) int   i32x4;

// ---------------------------------------------------------------------------
// B=2, C=64, H=W=64, N=4096, dk=8.
// Sobel weights are broadcast over [C,C,3,3] -> conv output = conv(chansum).
// Keys/queries affine in scalar field e[n]; softmax row m = softmax_n(t_m*e[n]),
// t_m = alpha*eq[m]+gamma; row max = t*e_max (t>0) else t*e_min -> K-split
// partials add with a COMMON max (no flash rescale needed).
// scal layout (floats): [0..3] alpha_vi,gamma_vi,alpha_ir,gamma_ir;
//   [16..143]  per-block min e: [bm=b*2+mod][rt=0..31]
//   [144..271] per-block max e: [bm][rt]
// 2 graph nodes total: kP (prep, zeros tickets) -> k4 (attn + ticket combine).
// ---------------------------------------------------------------------------

// kP: fused prep. Blocks 0..255: values 1x1-conv GEMM. Blocks 256..319:
// chansum -> sobel -> e fields + per-block min/max slots + alpha/gamma.
// Block 256 also zeros the 64 ticket counters for k4 (replay-safe).
__global__ __launch_bounds__(256) void kP_prep(
    const float* __restrict__ vi, const float* __restrict__ ir,
    const float* __restrict__ wsx_vi, const float* __restrict__ wsy_vi,
    const float* __restrict__ wsx_q,  const float* __restrict__ wsy_q,
    const float* __restrict__ wsx_ir, const float* __restrict__ wsy_ir,
    const float* __restrict__ w1_vi, const float* __restrict__ w1_q,
    const float* __restrict__ b1_q,  const float* __restrict__ w1_ir,
    const float* __restrict__ wv_vi, const float* __restrict__ bv_vi,
    const float* __restrict__ wv_ir, const float* __restrict__ bv_ir,
    float* __restrict__ e, float* __restrict__ scal,
    __hip_bfloat16* __restrict__ Vc, int* __restrict__ cnt) {
    const int t = threadIdx.x;
    if (blockIdx.x < 256) {
        // ---------------- values GEMM: V[c,n] = W[c,:] x[:,n] + b ----------
        __shared__ __align__(16) char wlds[64 * 128];   // 64x64 bf16 swizzled
        const int bm = blockIdx.x >> 6, nt = blockIdx.x & 63;
        const int b = bm >> 1, mod = bm & 1;
        const float* wv = mod ? wv_ir : wv_vi;
        const float* bv = mod ? bv_ir : bv_vi;
        const float* x = (mod ? ir : vi) + b * (64 * 4096);
        {
            const float* src = wv + t * 16;
            int row = t >> 2, colb = (t & 3) * 32;
            int pk[8];
            #pragma unroll
            for (int j = 0; j < 8; ++j)
                asm("v_cvt_pk_bf16_f32 %0, %1, %2" : "=v"(pk[j])
                    : "v"(src[2 * j]), "v"(src[2 * j + 1]));
            int sw = (row & 7) << 4;
            i32x4 lo = {pk[0], pk[1], pk[2], pk[3]};
            i32x4 hi = {pk[4], pk[5], pk[6], pk[7]};
            *(i32x4*)(wlds + row * 128 + (colb ^ sw)) = lo;
            *(i32x4*)(wlds + row * 128 + ((colb + 16) ^ sw)) = hi;
        }
        __syncthreads();
        const int wvid = t >> 6, lane = t & 63;
        const int col = lane & 15, g = lane >> 4;
        const int n = nt * 64 + wvid * 16 + col;
        bf16x8 afr[4][2];
        #pragma unroll
        for (int cb = 0; cb < 4; ++cb) {
            int row = cb * 16 + col;
            int sw = (row & 7) << 4;
            #pragma unroll
            for (int ks = 0; ks < 2; ++ks)
                afr[cb][ks] = *(const bf16x8*)(wlds + row * 128 + ((ks * 64 + g * 16) ^ sw));
        }
        bf16x8 bfr[2];
        #pragma unroll
        for (int ks = 0; ks < 2; ++ks) {
            const float* xr = x + (ks * 32 + g * 8) * 4096 + n;
            int pk[4];
            #pragma unroll
            for (int j = 0; j < 4; ++j)
                asm("v_cvt_pk_bf16_f32 %0, %1, %2" : "=v"(pk[j])
                    : "v"(xr[(2 * j) * 4096]), "v"(xr[(2 * j + 1) * 4096]));
            i32x4 bi = {pk[0], pk[1], pk[2], pk[3]};
            bfr[ks] = __builtin_bit_cast(bf16x8, bi);
        }
        f32x4 acc[4];
        #pragma unroll
        for (int cb = 0; cb < 4; ++cb)
            #pragma unroll
            for (int r = 0; r < 4; ++r) acc[cb][r] = bv[cb * 16 + g * 4 + r];
        #pragma unroll
        for (int ks = 0; ks < 2; ++ks)
            #pragma unroll
            for (int cb = 0; cb < 4; ++cb)
                acc[cb] = __builtin_amdgcn_mfma_f32_16x16x32_bf16(afr[cb][ks], bfr[ks], acc[cb], 0, 0, 0);
        __hip_bfloat16* outp = Vc + (size_t)(bm * 64) * 4096 + n;
        #pragma unroll
        for (int cb = 0; cb < 4; ++cb)
            #pragma unroll
            for (int r = 0; r < 4; ++r)
                outp[(cb * 16 + g * 4 + r) * 4096] = __float2bfloat16(acc[cb][r]);
    } else {
        // ---------------- chansum -> sobel -> e, min/max slots --------------
        __shared__ float sv[256], si[256];       // 4 rows x 64 cols per mod
        __shared__ float Ad[8], Cv[8], Ci[8], Bq[8];
        __shared__ float mmred[8];
        const int id = blockIdx.x - 256;
        const int rt = id & 31, b = id >> 5;
        const int r0 = rt * 2;
        const float* xv = vi + b * 64 * 4096;
        const float* xi = ir + b * 64 * 4096;
        if (id == 0 && t < 64) cnt[t] = 0;       // zero k4 ticket counters
        if (b == 0 && rt == 0 && t < 8) {
            float a = 0.f;
            for (int c = 0; c < 128; ++c) a += w1_q[t * 128 + c];
            float cv = 0.f, ci = 0.f;
            for (int c = 0; c < 64; ++c) { cv += w1_vi[t * 64 + c]; ci += w1_ir[t * 64 + c]; }
            Ad[t] = a; Cv[t] = cv; Ci[t] = ci; Bq[t] = b1_q[t];
        }
        #pragma unroll
        for (int k = 0; k < 2; ++k) {
            int id2 = t + k * 256;
            int mod = id2 >> 8;
            int entry = id2 & 255;
            int grow = r0 - 1 + (entry >> 6);
            int col = entry & 63;
            float acc = 0.f;
            if (grow >= 0 && grow < 64) {
                const float* x = (mod ? xi : xv) + grow * 64 + col;
                #pragma unroll 16
                for (int c = 0; c < 64; ++c) acc += x[c * 4096];
            }
            (mod ? si : sv)[entry] = acc;
        }
        __syncthreads();
        if (b == 0 && rt == 0 && t == 0) {
            float av = 0, gv = 0, ai = 0, gi = 0;
            for (int d = 0; d < 8; ++d) {
                av += Ad[d] * Cv[d]; gv += Bq[d] * Cv[d];
                ai += Ad[d] * Ci[d]; gi += Bq[d] * Ci[d];
            }
            scal[0] = av; scal[1] = gv; scal[2] = ai; scal[3] = gi;
        }
        if (t < 128) {
            int row = t >> 6, col = t & 63;
            int n = (r0 + row) * 64 + col;
            float nv[3][3], ni[3][3];
            #pragma unroll
            for (int di = 0; di < 3; ++di)
                #pragma unroll
                for (int dj = 0; dj < 3; ++dj) {
                    int cc = col + dj - 1;
                    bool in = (cc >= 0) & (cc < 64);
                    int idx = (row + di) * 64 + (in ? cc : 0);
                    nv[di][dj] = in ? sv[idx] : 0.f;
                    ni[di][dj] = in ? si[idx] : 0.f;
                }
            float gxv = 0, gyv = 0, gxi = 0, gyi = 0, gxq = 0, gyq = 0;
            #pragma unroll
            for (int i = 0; i < 3; ++i)
                #pragma unroll
                for (int j = 0; j < 3; ++j) {
                    int k = i * 3 + j;
                    gxv += nv[i][j] * wsx_vi[k]; gyv += nv[i][j] * wsy_vi[k];
                    gxi += ni[i][j] * wsx_ir[k]; gyi += ni[i][j] * wsy_ir[k];
                    float q = nv[i][j] + ni[i][j];
                    gxq += q * wsx_q[k]; gyq += q * wsy_q[k];
                }
            float ev = fabsf(gxv) + fabsf(gyv);
            float ei = fabsf(gxi) + fabsf(gyi);
            float eq = fabsf(gxq) + fabsf(gyq);
            e[(b * 3 + 0) * 4096 + n] = ev;
            e[(b * 3 + 1) * 4096 + n] = ei;
            e[(b * 3 + 2) * 4096 + n] = eq;
            float mnv = ev, mxv = ev, mni = ei, mxi = ei;
            for (int o = 32; o; o >>= 1) {
                mnv = fminf(mnv, __shfl_down(mnv, o));
                mxv = fmaxf(mxv, __shfl_down(mxv, o));
                mni = fminf(mni, __shfl_down(mni, o));
                mxi = fmaxf(mxi, __shfl_down(mxi, o));
            }
            if ((t & 63) == 0) {
                int w = t >> 6;
                mmred[w * 4 + 0] = mnv; mmred[w * 4 + 1] = mxv;
                mmred[w * 4 + 2] = mni; mmred[w * 4 + 3] = mxi;
            }
        }
        __syncthreads();
        if (t == 0) {
            float* bmn = scal + 16;
            float* bmx = scal + 144;
            bmn[(b * 2 + 0) * 32 + rt] = fminf(mmred[0], mmred[4]);
            bmx[(b * 2 + 0) * 32 + rt] = fmaxf(mmred[1], mmred[5]);
            bmn[(b * 2 + 1) * 32 + rt] = fminf(mmred[2], mmred[6]);
            bmx[(b * 2 + 1) * 32 + rt] = fmaxf(mmred[3], mmred[7]);
        }
    }
}

// k4: O[c,m] = sum_n V[c,n] * 2^(t2_m*e[n] - M2_m);  Z via ones-MFMA.
// V K-chunk (64x1024 bf16, 128KB) + e chunk staged in LDS (XOR-swizzled);
// inner loop LDS+VALU+MFMA only; MT=4 m-tiles reuse each V fragment.
// Epilogue: last block per (bw, mt8) (ticket==3) combines the 4 sp-partials
// in fixed order and writes the final normalized output (replaces k5 node).
#define KLEN 1024
#define MT 4
__global__ __launch_bounds__(256, 1) void k4_attn(
        const float* __restrict__ e, const float* __restrict__ scal,
        const __hip_bfloat16* __restrict__ Vc,
        float* __restrict__ Opart, float* __restrict__ Zpart,
        float* __restrict__ out, int* __restrict__ cnt) {
    __shared__ __align__(16) char vbuf[64 * KLEN * 2];   // 128 KB swizzled
    __shared__ __align__(16) float elds[KLEN];           // 4 KB
    __shared__ int tick;
    const int mt8 = blockIdx.x;   // 16 groups of 256 m
    const int bw  = blockIdx.y;   // b*2+which
    const int sp  = blockIdx.z;   // 4 K-splits
    const int b = bw >> 1, which = bw & 1;
    const int amod = which ? 0 : 1;
    const int vmod = which;
    const float* e_att = e + (b * 3 + amod) * 4096;
    const float* e_q   = e + (b * 3 + 2) * 4096;
    const float alpha = scal[which ? 0 : 2];
    const float gamma = scal[which ? 1 : 3];
    const short* Vg = (const short*)(Vc + (size_t)((b * 2 + vmod) * 64) * 4096);

    const int tid = threadIdx.x;
    const int wv = tid >> 6, lane = tid & 63;

    // global min/max of e field: lane-parallel reduce of 32 per-block slots
    float emn = scal[16  + (b * 2 + amod) * 32 + (lane & 31)];
    float emx = scal[144 + (b * 2 + amod) * 32 + (lane & 31)];
    #pragma unroll
    for (int o = 16; o; o >>= 1) {
        emn = fminf(emn, __shfl_xor(emn, o));
        emx = fmaxf(emx, __shfl_xor(emx, o));
    }

    #pragma unroll
    for (int k = 0; k < 32; ++k) {
        int id = tid + k * 256;
        int c = id >> 7, s = id & 127;
        bf16x8 v = *(const bf16x8*)(Vg + c * 4096 + sp * KLEN + s * 8);
        int dst = c * 2048 + ((s * 16) ^ ((c & 31) << 4));
        *(bf16x8*)(vbuf + dst) = v;
    }
    {
        f32x4 ev = *(const f32x4*)(e_att + sp * KLEN + tid * 4);
        *(f32x4*)(elds + tid * 4) = ev;
    }
    __syncthreads();

    const int col = lane & 15, g = lane >> 4;
    const float L2E = 1.4426950408889634f;
    float t2[MT], nM2[MT];
    int mbase[MT];
    #pragma unroll
    for (int mt = 0; mt < MT; ++mt) {
        int m = mt8 * 256 + mt * 64 + wv * 16 + col;
        mbase[mt] = m;
        float t = alpha * e_q[m] + gamma;
        t2[mt]  = t * L2E;
        nM2[mt] = -((t > 0.f) ? t * emx : t * emn) * L2E;
    }

    f32x4 acc[MT][4] = {};
    f32x4 accz[MT] = {};
    bf16x8 ones;
    #pragma unroll
    for (int j = 0; j < 8; ++j) ones[j] = (short)0x3F80;

    for (int it = 0; it < KLEN / 32; ++it) {
        const int n0 = it * 32;
        bf16x8 af[4];
        #pragma unroll
        for (int cb = 0; cb < 4; ++cb) {
            int row = cb * 16 + col;
            int byte = row * 2048 + (((n0 + g * 8) * 2) ^ ((row & 31) << 4));
            af[cb] = *(const bf16x8*)(vbuf + byte);
        }
        f32x4 e0 = *(const f32x4*)(elds + n0 + g * 8);
        f32x4 e1 = *(const f32x4*)(elds + n0 + g * 8 + 4);
        #pragma unroll
        for (int mt = 0; mt < MT; ++mt) {
            float p[8];
            #pragma unroll
            for (int j = 0; j < 4; ++j) {
                float g0 = fmaf(e0[j], t2[mt], nM2[mt]);
                float g1 = fmaf(e1[j], t2[mt], nM2[mt]);
                asm("v_exp_f32 %0, %1" : "=v"(p[j])     : "v"(g0));
                asm("v_exp_f32 %0, %1" : "=v"(p[j + 4]) : "v"(g1));
            }
            int pk0, pk1, pk2, pk3;
            asm("v_cvt_pk_bf16_f32 %0, %1, %2" : "=v"(pk0) : "v"(p[0]), "v"(p[1]));
            asm("v_cvt_pk_bf16_f32 %0, %1, %2" : "=v"(pk1) : "v"(p[2]), "v"(p[3]));
            asm("v_cvt_pk_bf16_f32 %0, %1, %2" : "=v"(pk2) : "v"(p[4]), "v"(p[5]));
            asm("v_cvt_pk_bf16_f32 %0, %1, %2" : "=v"(pk3) : "v"(p[6]), "v"(p[7]));
            i32x4 pki = {pk0, pk1, pk2, pk3};
            bf16x8 bfrag = __builtin_bit_cast(bf16x8, pki);
            #pragma unroll
            for (int cb = 0; cb < 4; ++cb)
                acc[mt][cb] = __builtin_amdgcn_mfma_f32_16x16x32_bf16(af[cb], bfrag, acc[mt][cb], 0, 0, 0);
            accz[mt] = __builtin_amdgcn_mfma_f32_16x16x32_bf16(ones, bfrag, accz[mt], 0, 0, 0);
        }
    }

    float* opb = Opart + (size_t)((bw * 4 + sp) * 64) * 4096;
    #pragma unroll
    for (int mt = 0; mt < MT; ++mt) {
        float* op = opb + mbase[mt];
        #pragma unroll
        for (int cb = 0; cb < 4; ++cb) {
            int c = cb * 16 + g * 4;
            #pragma unroll
            for (int r = 0; r < 4; ++r) op[(c + r) * 4096] = acc[mt][cb][r];
        }
        if (lane < 16) Zpart[(bw * 4 + sp) * 4096 + mbase[mt]] = accz[mt][0];
    }

    // ---- ticket epilogue: last of the 4 sp blocks combines this region ----
    __threadfence();                       // release: all threads' stores
    __syncthreads();
    if (tid == 0) tick = atomicAdd(&cnt[bw * 16 + mt8], 1);
    __syncthreads();
    if (tick == 3) {
        __threadfence();                   // acquire: see other blocks' stores
        const int w = tid >> 6;
        const int l2 = tid & 63;
        const int m4 = mt8 * 256 + l2 * 4;
        const float* zb = Zpart + bw * 4 * 4096;
        f32x4 den = {};
        #pragma unroll
        for (int sp2 = 0; sp2 < 4; ++sp2)
            den += *(const f32x4*)(zb + sp2 * 4096 + m4);
        float* ob = out + which * (2 * 64 * 4096) + b * (64 * 4096);
        const float* opb2 = Opart + (size_t)(bw * 4) * 64 * 4096;
        for (int c = w; c < 64; c += 4) {
            f32x4 num = {};
            #pragma unroll
            for (int sp2 = 0; sp2 < 4; ++sp2)
                num += *(const f32x4*)(opb2 + ((size_t)(sp2 * 64 + c)) * 4096 + m4);
            *(f32x4*)(ob + c * 4096 + m4) = num / den;
        }
    }
}

extern "C" void kernel_launch(void* const* d_in, const int* in_sizes, int n_in,
                              void* d_out, int out_size, void* d_ws, size_t ws_size,
                              hipStream_t stream) {
    const float* vi     = (const float*)d_in[0];
    const float* ir     = (const float*)d_in[1];
    const float* wsx_vi = (const float*)d_in[2];
    const float* wsy_vi = (const float*)d_in[3];
    const float* w1_vi  = (const float*)d_in[4];
    const float* wsx_q  = (const float*)d_in[6];
    const float* wsy_q  = (const float*)d_in[7];
    const float* w1_q   = (const float*)d_in[8];
    const float* b1_q   = (const float*)d_in[9];
    const float* wsx_ir = (const float*)d_in[10];
    const float* wsy_ir = (const float*)d_in[11];
    const float* w1_ir  = (const float*)d_in[12];
    const float* wv_vi  = (const float*)d_in[14];
    const float* bv_vi  = (const float*)d_in[15];
    const float* wv_ir  = (const float*)d_in[16];
    const float* bv_ir  = (const float*)d_in[17];
    (void)in_sizes; (void)n_in; (void)out_size;

    char* ws = (char*)d_ws;
    float* scal = (float*)ws;                              // 1088 B used
    float* e    = (float*)(ws + 1280);                     // 96 KB
    __hip_bfloat16* Vc = (__hip_bfloat16*)(ws + 99584);    // 2 MB
    float* Opart = (float*)(ws + 2196736);                 // 16 MB
    float* Zpart = (float*)(ws + 2196736 + 4ull * 4194304);
    int*   cnt   = (int*)(ws + 2196736 + 4ull * 4194304 + 262144);  // 64 ints
    float* out = (float*)d_out;
    (void)ws_size;

    kP_prep<<<dim3(320), 256, 0, stream>>>(vi, ir, wsx_vi, wsy_vi, wsx_q, wsy_q,
                                           wsx_ir, wsy_ir, w1_vi, w1_q, b1_q, w1_ir,
                                           wv_vi, bv_vi, wv_ir, bv_ir, e, scal, Vc, cnt);
    k4_attn<<<dim3(16, 4, 4), 256, 0, stream>>>(e, scal, Vc, Opart, Zpart, out, cnt);
}

// Round 7
// 37.012 us; speedup vs baseline: 2.2123x; 2.2123x over previous
//
#include <hip/hip_runtime.h>
#include <hip/hip_bf16.h>

typedef __attribute__((ext_vector_type(8))) short bf16x8;
typedef __attribute__((ext_vector_type(4))) float f32x4;
typedef __attribute__((ext_vector_type(4))) int   i32x4;

// ---------------------------------------------------------------------------
// B=2, C=64, H=W=64, N=4096, dk=8.
// Sobel weights are broadcast over [C,C,3,3] -> conv output = conv(chansum).
// Keys/queries affine in scalar field e[n]; softmax row m = softmax_n(t_m*e[n]),
// t_m = alpha*eq[m]+gamma; row max = t*e_max (t>0) else t*e_min -> K-split
// partials add with a COMMON max (no flash rescale needed).
// scal layout (floats): [0..3] alpha_vi,gamma_vi,alpha_ir,gamma_ir;
//   [16..143]  per-block min e: [bm=b*2+mod][rt=0..31]
//   [144..271] per-block max e: [bm][rt]
// 3 graph nodes: kP (prep) -> k4 (attn, partials) -> k5 (combine).
// NOTE R6 lesson: intra-kernel cross-block combine via __threadfence costs
// ~2x the whole pipeline (per-block L2 flush on gfx950). Keep kernel-boundary
// coherence only.
// ---------------------------------------------------------------------------

// kP: fused prep. Blocks 0..255: values 1x1-conv GEMM. Blocks 256..319:
// chansum -> sobel -> e fields + per-block min/max slots + alpha/gamma.
__global__ __launch_bounds__(256) void kP_prep(
    const float* __restrict__ vi, const float* __restrict__ ir,
    const float* __restrict__ wsx_vi, const float* __restrict__ wsy_vi,
    const float* __restrict__ wsx_q,  const float* __restrict__ wsy_q,
    const float* __restrict__ wsx_ir, const float* __restrict__ wsy_ir,
    const float* __restrict__ w1_vi, const float* __restrict__ w1_q,
    const float* __restrict__ b1_q,  const float* __restrict__ w1_ir,
    const float* __restrict__ wv_vi, const float* __restrict__ bv_vi,
    const float* __restrict__ wv_ir, const float* __restrict__ bv_ir,
    float* __restrict__ e, float* __restrict__ scal,
    __hip_bfloat16* __restrict__ Vc) {
    const int t = threadIdx.x;
    if (blockIdx.x < 256) {
        // ---------------- values GEMM: V[c,n] = W[c,:] x[:,n] + b ----------
        __shared__ __align__(16) char wlds[64 * 128];   // 64x64 bf16 swizzled
        const int bm = blockIdx.x >> 6, nt = blockIdx.x & 63;
        const int b = bm >> 1, mod = bm & 1;
        const float* wv = mod ? wv_ir : wv_vi;
        const float* bv = mod ? bv_ir : bv_vi;
        const float* x = (mod ? ir : vi) + b * (64 * 4096);
        {
            const float* src = wv + t * 16;
            int row = t >> 2, colb = (t & 3) * 32;
            int pk[8];
            #pragma unroll
            for (int j = 0; j < 8; ++j)
                asm("v_cvt_pk_bf16_f32 %0, %1, %2" : "=v"(pk[j])
                    : "v"(src[2 * j]), "v"(src[2 * j + 1]));
            int sw = (row & 7) << 4;
            i32x4 lo = {pk[0], pk[1], pk[2], pk[3]};
            i32x4 hi = {pk[4], pk[5], pk[6], pk[7]};
            *(i32x4*)(wlds + row * 128 + (colb ^ sw)) = lo;
            *(i32x4*)(wlds + row * 128 + ((colb + 16) ^ sw)) = hi;
        }
        __syncthreads();
        const int wvid = t >> 6, lane = t & 63;
        const int col = lane & 15, g = lane >> 4;
        const int n = nt * 64 + wvid * 16 + col;
        bf16x8 afr[4][2];
        #pragma unroll
        for (int cb = 0; cb < 4; ++cb) {
            int row = cb * 16 + col;
            int sw = (row & 7) << 4;
            #pragma unroll
            for (int ks = 0; ks < 2; ++ks)
                afr[cb][ks] = *(const bf16x8*)(wlds + row * 128 + ((ks * 64 + g * 16) ^ sw));
        }
        bf16x8 bfr[2];
        #pragma unroll
        for (int ks = 0; ks < 2; ++ks) {
            const float* xr = x + (ks * 32 + g * 8) * 4096 + n;
            int pk[4];
            #pragma unroll
            for (int j = 0; j < 4; ++j)
                asm("v_cvt_pk_bf16_f32 %0, %1, %2" : "=v"(pk[j])
                    : "v"(xr[(2 * j) * 4096]), "v"(xr[(2 * j + 1) * 4096]));
            i32x4 bi = {pk[0], pk[1], pk[2], pk[3]};
            bfr[ks] = __builtin_bit_cast(bf16x8, bi);
        }
        f32x4 acc[4];
        #pragma unroll
        for (int cb = 0; cb < 4; ++cb)
            #pragma unroll
            for (int r = 0; r < 4; ++r) acc[cb][r] = bv[cb * 16 + g * 4 + r];
        #pragma unroll
        for (int ks = 0; ks < 2; ++ks)
            #pragma unroll
            for (int cb = 0; cb < 4; ++cb)
                acc[cb] = __builtin_amdgcn_mfma_f32_16x16x32_bf16(afr[cb][ks], bfr[ks], acc[cb], 0, 0, 0);
        __hip_bfloat16* outp = Vc + (size_t)(bm * 64) * 4096 + n;
        #pragma unroll
        for (int cb = 0; cb < 4; ++cb)
            #pragma unroll
            for (int r = 0; r < 4; ++r)
                outp[(cb * 16 + g * 4 + r) * 4096] = __float2bfloat16(acc[cb][r]);
    } else {
        // ---------------- chansum -> sobel -> e, min/max slots --------------
        __shared__ float sv[256], si[256];       // 4 rows x 64 cols per mod
        __shared__ float Ad[8], Cv[8], Ci[8], Bq[8];
        __shared__ float mmred[8];
        const int id = blockIdx.x - 256;
        const int rt = id & 31, b = id >> 5;
        const int r0 = rt * 2;
        const float* xv = vi + b * 64 * 4096;
        const float* xi = ir + b * 64 * 4096;
        if (b == 0 && rt == 0 && t < 8) {
            float a = 0.f;
            for (int c = 0; c < 128; ++c) a += w1_q[t * 128 + c];
            float cv = 0.f, ci = 0.f;
            for (int c = 0; c < 64; ++c) { cv += w1_vi[t * 64 + c]; ci += w1_ir[t * 64 + c]; }
            Ad[t] = a; Cv[t] = cv; Ci[t] = ci; Bq[t] = b1_q[t];
        }
        #pragma unroll
        for (int k = 0; k < 2; ++k) {
            int id2 = t + k * 256;
            int mod = id2 >> 8;
            int entry = id2 & 255;
            int grow = r0 - 1 + (entry >> 6);
            int col = entry & 63;
            float acc = 0.f;
            if (grow >= 0 && grow < 64) {
                const float* x = (mod ? xi : xv) + grow * 64 + col;
                #pragma unroll 16
                for (int c = 0; c < 64; ++c) acc += x[c * 4096];
            }
            (mod ? si : sv)[entry] = acc;
        }
        __syncthreads();
        if (b == 0 && rt == 0 && t == 0) {
            float av = 0, gv = 0, ai = 0, gi = 0;
            for (int d = 0; d < 8; ++d) {
                av += Ad[d] * Cv[d]; gv += Bq[d] * Cv[d];
                ai += Ad[d] * Ci[d]; gi += Bq[d] * Ci[d];
            }
            scal[0] = av; scal[1] = gv; scal[2] = ai; scal[3] = gi;
        }
        if (t < 128) {
            int row = t >> 6, col = t & 63;
            int n = (r0 + row) * 64 + col;
            float nv[3][3], ni[3][3];
            #pragma unroll
            for (int di = 0; di < 3; ++di)
                #pragma unroll
                for (int dj = 0; dj < 3; ++dj) {
                    int cc = col + dj - 1;
                    bool in = (cc >= 0) & (cc < 64);
                    int idx = (row + di) * 64 + (in ? cc : 0);
                    nv[di][dj] = in ? sv[idx] : 0.f;
                    ni[di][dj] = in ? si[idx] : 0.f;
                }
            float gxv = 0, gyv = 0, gxi = 0, gyi = 0, gxq = 0, gyq = 0;
            #pragma unroll
            for (int i = 0; i < 3; ++i)
                #pragma unroll
                for (int j = 0; j < 3; ++j) {
                    int k = i * 3 + j;
                    gxv += nv[i][j] * wsx_vi[k]; gyv += nv[i][j] * wsy_vi[k];
                    gxi += ni[i][j] * wsx_ir[k]; gyi += ni[i][j] * wsy_ir[k];
                    float q = nv[i][j] + ni[i][j];
                    gxq += q * wsx_q[k]; gyq += q * wsy_q[k];
                }
            float ev = fabsf(gxv) + fabsf(gyv);
            float ei = fabsf(gxi) + fabsf(gyi);
            float eq = fabsf(gxq) + fabsf(gyq);
            e[(b * 3 + 0) * 4096 + n] = ev;
            e[(b * 3 + 1) * 4096 + n] = ei;
            e[(b * 3 + 2) * 4096 + n] = eq;
            float mnv = ev, mxv = ev, mni = ei, mxi = ei;
            for (int o = 32; o; o >>= 1) {
                mnv = fminf(mnv, __shfl_down(mnv, o));
                mxv = fmaxf(mxv, __shfl_down(mxv, o));
                mni = fminf(mni, __shfl_down(mni, o));
                mxi = fmaxf(mxi, __shfl_down(mxi, o));
            }
            if ((t & 63) == 0) {
                int w = t >> 6;
                mmred[w * 4 + 0] = mnv; mmred[w * 4 + 1] = mxv;
                mmred[w * 4 + 2] = mni; mmred[w * 4 + 3] = mxi;
            }
        }
        __syncthreads();
        if (t == 0) {
            float* bmn = scal + 16;
            float* bmx = scal + 144;
            bmn[(b * 2 + 0) * 32 + rt] = fminf(mmred[0], mmred[4]);
            bmx[(b * 2 + 0) * 32 + rt] = fmaxf(mmred[1], mmred[5]);
            bmn[(b * 2 + 1) * 32 + rt] = fminf(mmred[2], mmred[6]);
            bmx[(b * 2 + 1) * 32 + rt] = fmaxf(mmred[3], mmred[7]);
        }
    }
}

// k4: O[c,m] = sum_n V[c,n] * 2^(t2_m*e[n] - M2_m);  Z via ones-MFMA.
// 512 threads = 8 waves = (h in {0,1} K-halves) x (wvt in [0,4) m-row tiles).
// Each wave: MT=4 m-tiles, 16 of the 32 K-iters -> 2 waves/SIMD occupancy
// with unchanged total LDS reads and VALU work. K-half partials combined
// through LDS (vbuf reused after sync); h==0 waves write Opart/Zpart.
#define KLEN 1024
#define MT 4
__global__ __launch_bounds__(512, 2) void k4_attn(
        const float* __restrict__ e, const float* __restrict__ scal,
        const __hip_bfloat16* __restrict__ Vc,
        float* __restrict__ Opart, float* __restrict__ Zpart) {
    __shared__ __align__(16) char vbuf[64 * KLEN * 2];   // 128 KB swizzled
    __shared__ __align__(16) float elds[KLEN];           // 4 KB
    const int mt8 = blockIdx.x;   // 16 groups of 256 m
    const int bw  = blockIdx.y;   // b*2+which
    const int sp  = blockIdx.z;   // 4 K-splits
    const int b = bw >> 1, which = bw & 1;
    const int amod = which ? 0 : 1;
    const int vmod = which;
    const float* e_att = e + (b * 3 + amod) * 4096;
    const float* e_q   = e + (b * 3 + 2) * 4096;
    const float alpha = scal[which ? 0 : 2];
    const float gamma = scal[which ? 1 : 3];
    const short* Vg = (const short*)(Vc + (size_t)((b * 2 + vmod) * 64) * 4096);

    const int tid = threadIdx.x;
    const int wvw = tid >> 6, lane = tid & 63;
    const int h = wvw >> 2, wvt = wvw & 3;       // K-half, m-row tile

    // global min/max of e field: lane-parallel reduce of 32 per-block slots
    float emn = scal[16  + (b * 2 + amod) * 32 + (lane & 31)];
    float emx = scal[144 + (b * 2 + amod) * 32 + (lane & 31)];
    #pragma unroll
    for (int o = 16; o; o >>= 1) {
        emn = fminf(emn, __shfl_xor(emn, o));
        emx = fmaxf(emx, __shfl_xor(emx, o));
    }

    #pragma unroll
    for (int k = 0; k < 16; ++k) {               // 8192 16B chunks / 512 thr
        int id = tid + k * 512;
        int c = id >> 7, s = id & 127;
        bf16x8 v = *(const bf16x8*)(Vg + c * 4096 + sp * KLEN + s * 8);
        int dst = c * 2048 + ((s * 16) ^ ((c & 31) << 4));
        *(bf16x8*)(vbuf + dst) = v;
    }
    if (tid < 256) {
        f32x4 ev = *(const f32x4*)(e_att + sp * KLEN + tid * 4);
        *(f32x4*)(elds + tid * 4) = ev;
    }
    __syncthreads();

    const int col = lane & 15, g = lane >> 4;
    const float L2E = 1.4426950408889634f;
    float t2[MT], nM2[MT];
    int mbase[MT];
    #pragma unroll
    for (int mt = 0; mt < MT; ++mt) {
        int m = mt8 * 256 + mt * 64 + wvt * 16 + col;
        mbase[mt] = m;
        float t = alpha * e_q[m] + gamma;
        t2[mt]  = t * L2E;
        nM2[mt] = -((t > 0.f) ? t * emx : t * emn) * L2E;
    }

    f32x4 acc[MT][4] = {};
    f32x4 accz[MT] = {};
    bf16x8 ones;
    #pragma unroll
    for (int j = 0; j < 8; ++j) ones[j] = (short)0x3F80;

    for (int it = h * 16; it < h * 16 + 16; ++it) {
        const int n0 = it * 32;
        bf16x8 af[4];
        #pragma unroll
        for (int cb = 0; cb < 4; ++cb) {
            int row = cb * 16 + col;
            int byte = row * 2048 + (((n0 + g * 8) * 2) ^ ((row & 31) << 4));
            af[cb] = *(const bf16x8*)(vbuf + byte);
        }
        f32x4 e0 = *(const f32x4*)(elds + n0 + g * 8);
        f32x4 e1 = *(const f32x4*)(elds + n0 + g * 8 + 4);
        #pragma unroll
        for (int mt = 0; mt < MT; ++mt) {
            float p[8];
            #pragma unroll
            for (int j = 0; j < 4; ++j) {
                float g0 = fmaf(e0[j], t2[mt], nM2[mt]);
                float g1 = fmaf(e1[j], t2[mt], nM2[mt]);
                asm("v_exp_f32 %0, %1" : "=v"(p[j])     : "v"(g0));
                asm("v_exp_f32 %0, %1" : "=v"(p[j + 4]) : "v"(g1));
            }
            int pk0, pk1, pk2, pk3;
            asm("v_cvt_pk_bf16_f32 %0, %1, %2" : "=v"(pk0) : "v"(p[0]), "v"(p[1]));
            asm("v_cvt_pk_bf16_f32 %0, %1, %2" : "=v"(pk1) : "v"(p[2]), "v"(p[3]));
            asm("v_cvt_pk_bf16_f32 %0, %1, %2" : "=v"(pk2) : "v"(p[4]), "v"(p[5]));
            asm("v_cvt_pk_bf16_f32 %0, %1, %2" : "=v"(pk3) : "v"(p[6]), "v"(p[7]));
            i32x4 pki = {pk0, pk1, pk2, pk3};
            bf16x8 bfrag = __builtin_bit_cast(bf16x8, pki);
            #pragma unroll
            for (int cb = 0; cb < 4; ++cb)
                acc[mt][cb] = __builtin_amdgcn_mfma_f32_16x16x32_bf16(af[cb], bfrag, acc[mt][cb], 0, 0, 0);
            accz[mt] = __builtin_amdgcn_mfma_f32_16x16x32_bf16(ones, bfrag, accz[mt], 0, 0, 0);
        }
    }

    // combine K-halves through LDS (vbuf is dead after the sync)
    __syncthreads();
    float* red = (float*)vbuf;   // [wvt][mt][lane] stride 20 floats (16 acc + z)
    if (h == 1) {
        #pragma unroll
        for (int mt = 0; mt < MT; ++mt) {
            int base = ((wvt * 4 + mt) * 64 + lane) * 20;
            #pragma unroll
            for (int cb = 0; cb < 4; ++cb)
                *(f32x4*)(red + base + cb * 4) = acc[mt][cb];
            red[base + 16] = accz[mt][0];
        }
    }
    __syncthreads();
    if (h == 0) {
        float* opb = Opart + (size_t)((bw * 4 + sp) * 64) * 4096;
        #pragma unroll
        for (int mt = 0; mt < MT; ++mt) {
            int base = ((wvt * 4 + mt) * 64 + lane) * 20;
            #pragma unroll
            for (int cb = 0; cb < 4; ++cb)
                acc[mt][cb] += *(const f32x4*)(red + base + cb * 4);
            float z = accz[mt][0] + red[base + 16];
            float* op = opb + mbase[mt];
            #pragma unroll
            for (int cb = 0; cb < 4; ++cb) {
                int c = cb * 16 + g * 4;
                #pragma unroll
                for (int r = 0; r < 4; ++r) op[(c + r) * 4096] = acc[mt][cb][r];
            }
            if (lane < 16) Zpart[(bw * 4 + sp) * 4096 + mbase[mt]] = z;
        }
    }
}

// k5: combine K-split partials and normalize (vectorized, S=4).
__global__ __launch_bounds__(256) void k5_combine(
        const float* __restrict__ Opart, const float* __restrict__ Zpart,
        float* __restrict__ out) {
    int bw = blockIdx.y; int b = bw >> 1, which = bw & 1;
    int idx = (blockIdx.x * 256 + threadIdx.x) * 4;
    int m = idx & 4095;
    f32x4 num = {}; f32x4 den = {};
    #pragma unroll
    for (int sp = 0; sp < 4; ++sp) {
        num += *(const f32x4*)(Opart + (size_t)((bw * 4 + sp) * 64) * 4096 + idx);
        den += *(const f32x4*)(Zpart + (bw * 4 + sp) * 4096 + m);
    }
    *(f32x4*)(out + which * (2 * 64 * 4096) + b * (64 * 4096) + idx) = num / den;
}

extern "C" void kernel_launch(void* const* d_in, const int* in_sizes, int n_in,
                              void* d_out, int out_size, void* d_ws, size_t ws_size,
                              hipStream_t stream) {
    const float* vi     = (const float*)d_in[0];
    const float* ir     = (const float*)d_in[1];
    const float* wsx_vi = (const float*)d_in[2];
    const float* wsy_vi = (const float*)d_in[3];
    const float* w1_vi  = (const float*)d_in[4];
    const float* wsx_q  = (const float*)d_in[6];
    const float* wsy_q  = (const float*)d_in[7];
    const float* w1_q   = (const float*)d_in[8];
    const float* b1_q   = (const float*)d_in[9];
    const float* wsx_ir = (const float*)d_in[10];
    const float* wsy_ir = (const float*)d_in[11];
    const float* w1_ir  = (const float*)d_in[12];
    const float* wv_vi  = (const float*)d_in[14];
    const float* bv_vi  = (const float*)d_in[15];
    const float* wv_ir  = (const float*)d_in[16];
    const float* bv_ir  = (const float*)d_in[17];
    (void)in_sizes; (void)n_in; (void)out_size;

    char* ws = (char*)d_ws;
    float* scal = (float*)ws;                              // 1088 B used
    float* e    = (float*)(ws + 1280);                     // 96 KB
    __hip_bfloat16* Vc = (__hip_bfloat16*)(ws + 99584);    // 2 MB
    float* Opart = (float*)(ws + 2196736);                 // 16 MB
    float* Zpart = (float*)(ws + 2196736 + 4ull * 4194304);
    float* out = (float*)d_out;
    (void)ws_size;

    kP_prep<<<dim3(320), 256, 0, stream>>>(vi, ir, wsx_vi, wsy_vi, wsx_q, wsy_q,
                                           wsx_ir, wsy_ir, w1_vi, w1_q, b1_q, w1_ir,
                                           wv_vi, bv_vi, wv_ir, bv_ir, e, scal, Vc);
    k4_attn<<<dim3(16, 4, 4), 512, 0, stream>>>(e, scal, Vc, Opart, Zpart);
    k5_combine<<<dim3(256, 4), 256, 0, stream>>>(Opart, Zpart, out);
}

// Round 8
// 34.930 us; speedup vs baseline: 2.3442x; 1.0596x over previous
//
#include <hip/hip_runtime.h>
#include <hip/hip_bf16.h>

typedef __attribute__((ext_vector_type(8))) short bf16x8;
typedef __attribute__((ext_vector_type(4))) float f32x4;
typedef __attribute__((ext_vector_type(4))) int   i32x4;

// ---------------------------------------------------------------------------
// B=2, C=64, H=W=64, N=4096, dk=8.
// Sobel weights are broadcast over [C,C,3,3] -> conv output = conv(chansum).
// Keys/queries affine in scalar field e[n]; softmax row m = softmax_n(t_m*e[n]),
// t_m = alpha*eq[m]+gamma; row max = t*e_max (t>0) else t*e_min.
// scal layout (floats): [0..3] alpha_vi,gamma_vi,alpha_ir,gamma_ir;
//   [16..143] per-block min e [bm][rt], [144..271] per-block max e [bm][rt]
// 2 graph nodes: kP (prep) -> k4 (full-K attention, final output).
// R6 lesson: NO cross-block combine mid-kernel (__threadfence = per-block L2
// flush, 2x pipeline cost). All K now lives inside one block instead.
// ---------------------------------------------------------------------------

// kP: fused prep. Blocks 0..255: values 1x1-conv GEMM. Blocks 256..319:
// chansum -> sobel -> e fields + per-block min/max slots + alpha/gamma.
__global__ __launch_bounds__(256) void kP_prep(
    const float* __restrict__ vi, const float* __restrict__ ir,
    const float* __restrict__ wsx_vi, const float* __restrict__ wsy_vi,
    const float* __restrict__ wsx_q,  const float* __restrict__ wsy_q,
    const float* __restrict__ wsx_ir, const float* __restrict__ wsy_ir,
    const float* __restrict__ w1_vi, const float* __restrict__ w1_q,
    const float* __restrict__ b1_q,  const float* __restrict__ w1_ir,
    const float* __restrict__ wv_vi, const float* __restrict__ bv_vi,
    const float* __restrict__ wv_ir, const float* __restrict__ bv_ir,
    float* __restrict__ e, float* __restrict__ scal,
    __hip_bfloat16* __restrict__ Vc) {
    const int t = threadIdx.x;
    if (blockIdx.x < 256) {
        // ---------------- values GEMM: V[c,n] = W[c,:] x[:,n] + b ----------
        __shared__ __align__(16) char wlds[64 * 128];   // 64x64 bf16 swizzled
        const int bm = blockIdx.x >> 6, nt = blockIdx.x & 63;
        const int b = bm >> 1, mod = bm & 1;
        const float* wv = mod ? wv_ir : wv_vi;
        const float* bv = mod ? bv_ir : bv_vi;
        const float* x = (mod ? ir : vi) + b * (64 * 4096);
        {
            const float* src = wv + t * 16;
            int row = t >> 2, colb = (t & 3) * 32;
            int pk[8];
            #pragma unroll
            for (int j = 0; j < 8; ++j)
                asm("v_cvt_pk_bf16_f32 %0, %1, %2" : "=v"(pk[j])
                    : "v"(src[2 * j]), "v"(src[2 * j + 1]));
            int sw = (row & 7) << 4;
            i32x4 lo = {pk[0], pk[1], pk[2], pk[3]};
            i32x4 hi = {pk[4], pk[5], pk[6], pk[7]};
            *(i32x4*)(wlds + row * 128 + (colb ^ sw)) = lo;
            *(i32x4*)(wlds + row * 128 + ((colb + 16) ^ sw)) = hi;
        }
        __syncthreads();
        const int wvid = t >> 6, lane = t & 63;
        const int col = lane & 15, g = lane >> 4;
        const int n = nt * 64 + wvid * 16 + col;
        bf16x8 afr[4][2];
        #pragma unroll
        for (int cb = 0; cb < 4; ++cb) {
            int row = cb * 16 + col;
            int sw = (row & 7) << 4;
            #pragma unroll
            for (int ks = 0; ks < 2; ++ks)
                afr[cb][ks] = *(const bf16x8*)(wlds + row * 128 + ((ks * 64 + g * 16) ^ sw));
        }
        bf16x8 bfr[2];
        #pragma unroll
        for (int ks = 0; ks < 2; ++ks) {
            const float* xr = x + (ks * 32 + g * 8) * 4096 + n;
            int pk[4];
            #pragma unroll
            for (int j = 0; j < 4; ++j)
                asm("v_cvt_pk_bf16_f32 %0, %1, %2" : "=v"(pk[j])
                    : "v"(xr[(2 * j) * 4096]), "v"(xr[(2 * j + 1) * 4096]));
            i32x4 bi = {pk[0], pk[1], pk[2], pk[3]};
            bfr[ks] = __builtin_bit_cast(bf16x8, bi);
        }
        f32x4 acc[4];
        #pragma unroll
        for (int cb = 0; cb < 4; ++cb)
            #pragma unroll
            for (int r = 0; r < 4; ++r) acc[cb][r] = bv[cb * 16 + g * 4 + r];
        #pragma unroll
        for (int ks = 0; ks < 2; ++ks)
            #pragma unroll
            for (int cb = 0; cb < 4; ++cb)
                acc[cb] = __builtin_amdgcn_mfma_f32_16x16x32_bf16(afr[cb][ks], bfr[ks], acc[cb], 0, 0, 0);
        __hip_bfloat16* outp = Vc + (size_t)(bm * 64) * 4096 + n;
        #pragma unroll
        for (int cb = 0; cb < 4; ++cb)
            #pragma unroll
            for (int r = 0; r < 4; ++r)
                outp[(cb * 16 + g * 4 + r) * 4096] = __float2bfloat16(acc[cb][r]);
    } else {
        // ---------------- chansum -> sobel -> e, min/max slots --------------
        __shared__ float sv[256], si[256];       // 4 rows x 64 cols per mod
        __shared__ float Ad[8], Cv[8], Ci[8], Bq[8];
        __shared__ float mmred[8];
        const int id = blockIdx.x - 256;
        const int rt = id & 31, b = id >> 5;
        const int r0 = rt * 2;
        const float* xv = vi + b * 64 * 4096;
        const float* xi = ir + b * 64 * 4096;
        if (b == 0 && rt == 0 && t < 8) {
            float a = 0.f;
            for (int c = 0; c < 128; ++c) a += w1_q[t * 128 + c];
            float cv = 0.f, ci = 0.f;
            for (int c = 0; c < 64; ++c) { cv += w1_vi[t * 64 + c]; ci += w1_ir[t * 64 + c]; }
            Ad[t] = a; Cv[t] = cv; Ci[t] = ci; Bq[t] = b1_q[t];
        }
        #pragma unroll
        for (int k = 0; k < 2; ++k) {
            int id2 = t + k * 256;
            int mod = id2 >> 8;
            int entry = id2 & 255;
            int grow = r0 - 1 + (entry >> 6);
            int col = entry & 63;
            float acc = 0.f;
            if (grow >= 0 && grow < 64) {
                const float* x = (mod ? xi : xv) + grow * 64 + col;
                #pragma unroll 16
                for (int c = 0; c < 64; ++c) acc += x[c * 4096];
            }
            (mod ? si : sv)[entry] = acc;
        }
        __syncthreads();
        if (b == 0 && rt == 0 && t == 0) {
            float av = 0, gv = 0, ai = 0, gi = 0;
            for (int d = 0; d < 8; ++d) {
                av += Ad[d] * Cv[d]; gv += Bq[d] * Cv[d];
                ai += Ad[d] * Ci[d]; gi += Bq[d] * Ci[d];
            }
            scal[0] = av; scal[1] = gv; scal[2] = ai; scal[3] = gi;
        }
        if (t < 128) {
            int row = t >> 6, col = t & 63;
            int n = (r0 + row) * 64 + col;
            float nv[3][3], ni[3][3];
            #pragma unroll
            for (int di = 0; di < 3; ++di)
                #pragma unroll
                for (int dj = 0; dj < 3; ++dj) {
                    int cc = col + dj - 1;
                    bool in = (cc >= 0) & (cc < 64);
                    int idx = (row + di) * 64 + (in ? cc : 0);
                    nv[di][dj] = in ? sv[idx] : 0.f;
                    ni[di][dj] = in ? si[idx] : 0.f;
                }
            float gxv = 0, gyv = 0, gxi = 0, gyi = 0, gxq = 0, gyq = 0;
            #pragma unroll
            for (int i = 0; i < 3; ++i)
                #pragma unroll
                for (int j = 0; j < 3; ++j) {
                    int k = i * 3 + j;
                    gxv += nv[i][j] * wsx_vi[k]; gyv += nv[i][j] * wsy_vi[k];
                    gxi += ni[i][j] * wsx_ir[k]; gyi += ni[i][j] * wsy_ir[k];
                    float q = nv[i][j] + ni[i][j];
                    gxq += q * wsx_q[k]; gyq += q * wsy_q[k];
                }
            float ev = fabsf(gxv) + fabsf(gyv);
            float ei = fabsf(gxi) + fabsf(gyi);
            float eq = fabsf(gxq) + fabsf(gyq);
            e[(b * 3 + 0) * 4096 + n] = ev;
            e[(b * 3 + 1) * 4096 + n] = ei;
            e[(b * 3 + 2) * 4096 + n] = eq;
            float mnv = ev, mxv = ev, mni = ei, mxi = ei;
            for (int o = 32; o; o >>= 1) {
                mnv = fminf(mnv, __shfl_down(mnv, o));
                mxv = fmaxf(mxv, __shfl_down(mxv, o));
                mni = fminf(mni, __shfl_down(mni, o));
                mxi = fmaxf(mxi, __shfl_down(mxi, o));
            }
            if ((t & 63) == 0) {
                int w = t >> 6;
                mmred[w * 4 + 0] = mnv; mmred[w * 4 + 1] = mxv;
                mmred[w * 4 + 2] = mni; mmred[w * 4 + 3] = mxi;
            }
        }
        __syncthreads();
        if (t == 0) {
            float* bmn = scal + 16;
            float* bmx = scal + 144;
            bmn[(b * 2 + 0) * 32 + rt] = fminf(mmred[0], mmred[4]);
            bmx[(b * 2 + 0) * 32 + rt] = fmaxf(mmred[1], mmred[5]);
            bmn[(b * 2 + 1) * 32 + rt] = fminf(mmred[2], mmred[6]);
            bmx[(b * 2 + 1) * 32 + rt] = fmaxf(mmred[3], mmred[7]);
        }
    }
}

// k4: full-K attention per block. Each block: 64 m-rows, loops 8 K-chunks of
// 512 (double-buffered LDS: prefetch chunk k+1 into regs while computing k).
// 8 waves = (h: chunk K-half) x (wvt: 4 m-tiles of 16). Epilogue combines
// h-halves via LDS, normalizes by full-K Z, writes final output. No partials.
#define CH 512
#define NCH 8
__global__ __launch_bounds__(512, 2) void k4_attn(
        const float* __restrict__ e, const float* __restrict__ scal,
        const __hip_bfloat16* __restrict__ Vc,
        float* __restrict__ out) {
    __shared__ __align__(16) char vbuf[2][64 * CH * 2];  // 2 x 64 KB swizzled
    __shared__ __align__(16) float elds[2][CH];          // 2 x 2 KB
    const int mt = blockIdx.x;    // 64 m-groups of 64 rows
    const int bw = blockIdx.y;    // b*2+which
    const int b = bw >> 1, which = bw & 1;
    const int amod = which ? 0 : 1;
    const int vmod = which;
    const float* e_att = e + (b * 3 + amod) * 4096;
    const float* e_q   = e + (b * 3 + 2) * 4096;
    const float alpha = scal[which ? 0 : 2];
    const float gamma = scal[which ? 1 : 3];
    const short* Vg = (const short*)(Vc + (size_t)((b * 2 + vmod) * 64) * 4096);

    const int tid = threadIdx.x;
    const int wvw = tid >> 6, lane = tid & 63;
    const int h = wvw >> 2, wvt = wvw & 3;       // chunk K-half, m-tile
    const int col = lane & 15, g = lane >> 4;

    // global min/max of e field: lane-parallel reduce of 32 per-block slots
    float emn = scal[16  + (b * 2 + amod) * 32 + (lane & 31)];
    float emx = scal[144 + (b * 2 + amod) * 32 + (lane & 31)];
    #pragma unroll
    for (int o = 16; o; o >>= 1) {
        emn = fminf(emn, __shfl_xor(emn, o));
        emx = fmaxf(emx, __shfl_xor(emx, o));
    }

    const int m = mt * 64 + wvt * 16 + col;
    const float L2E = 1.4426950408889634f;
    const float t  = alpha * e_q[m] + gamma;
    const float t2 = t * L2E;
    const float nM2 = -((t > 0.f) ? t * emx : t * emn) * L2E;

    // prologue: stage chunk 0
    #pragma unroll
    for (int k = 0; k < 8; ++k) {
        int id = tid + k * 512;
        int c = id >> 6, s = id & 63;
        bf16x8 v = *(const bf16x8*)(Vg + c * 4096 + s * 8);
        *(bf16x8*)(vbuf[0] + c * 1024 + ((s * 16) ^ ((c & 31) << 4))) = v;
    }
    elds[0][tid] = e_att[tid];
    __syncthreads();

    f32x4 acc[4] = {};
    f32x4 accz = {};
    bf16x8 ones;
    #pragma unroll
    for (int j = 0; j < 8; ++j) ones[j] = (short)0x3F80;

    for (int ck = 0; ck < NCH; ++ck) {
        // prefetch next chunk into registers (overlaps with compute below)
        bf16x8 stg[8];
        float en = 0.f;
        const bool pf = (ck + 1 < NCH);
        if (pf) {
            const short* src = Vg + (ck + 1) * CH;
            #pragma unroll
            for (int k = 0; k < 8; ++k) {
                int id = tid + k * 512;
                int c = id >> 6, s = id & 63;
                stg[k] = *(const bf16x8*)(src + c * 4096 + s * 8);
            }
            en = e_att[(ck + 1) * CH + tid];
        }
        const char* vb = vbuf[ck & 1];
        const float* el = elds[ck & 1];
        #pragma unroll
        for (int it2 = 0; it2 < 8; ++it2) {
            const int n0 = (h * 8 + it2) * 32;
            bf16x8 af[4];
            #pragma unroll
            for (int cb = 0; cb < 4; ++cb) {
                int row = cb * 16 + col;
                int byte = row * 1024 + (((n0 + g * 8) * 2) ^ ((row & 31) << 4));
                af[cb] = *(const bf16x8*)(vb + byte);
            }
            f32x4 e0 = *(const f32x4*)(el + n0 + g * 8);
            f32x4 e1 = *(const f32x4*)(el + n0 + g * 8 + 4);
            float p[8];
            #pragma unroll
            for (int j = 0; j < 4; ++j) {
                float g0 = fmaf(e0[j], t2, nM2);
                float g1 = fmaf(e1[j], t2, nM2);
                asm("v_exp_f32 %0, %1" : "=v"(p[j])     : "v"(g0));
                asm("v_exp_f32 %0, %1" : "=v"(p[j + 4]) : "v"(g1));
            }
            int pk0, pk1, pk2, pk3;
            asm("v_cvt_pk_bf16_f32 %0, %1, %2" : "=v"(pk0) : "v"(p[0]), "v"(p[1]));
            asm("v_cvt_pk_bf16_f32 %0, %1, %2" : "=v"(pk1) : "v"(p[2]), "v"(p[3]));
            asm("v_cvt_pk_bf16_f32 %0, %1, %2" : "=v"(pk2) : "v"(p[4]), "v"(p[5]));
            asm("v_cvt_pk_bf16_f32 %0, %1, %2" : "=v"(pk3) : "v"(p[6]), "v"(p[7]));
            i32x4 pki = {pk0, pk1, pk2, pk3};
            bf16x8 bfrag = __builtin_bit_cast(bf16x8, pki);
            #pragma unroll
            for (int cb = 0; cb < 4; ++cb)
                acc[cb] = __builtin_amdgcn_mfma_f32_16x16x32_bf16(af[cb], bfrag, acc[cb], 0, 0, 0);
            accz = __builtin_amdgcn_mfma_f32_16x16x32_bf16(ones, bfrag, accz, 0, 0, 0);
        }
        __syncthreads();          // all waves done reading vbuf[ck&1^1] long ago
        if (pf) {
            char* wb = vbuf[(ck + 1) & 1];
            #pragma unroll
            for (int k = 0; k < 8; ++k) {
                int id = tid + k * 512;
                int c = id >> 6, s = id & 63;
                *(bf16x8*)(wb + c * 1024 + ((s * 16) ^ ((c & 31) << 4))) = stg[k];
            }
            elds[(ck + 1) & 1][tid] = en;
            __syncthreads();
        }
    }

    // combine the two chunk-halves through LDS, normalize, write final output
    float* red = (float*)vbuf[0];   // [wvt][lane] stride 21 floats
    if (h == 1) {
        int base = (wvt * 64 + lane) * 21;
        #pragma unroll
        for (int cb = 0; cb < 4; ++cb)
            *(f32x4*)(red + base + cb * 4) = acc[cb];
        red[base + 16] = accz[0];
    }
    __syncthreads();
    if (h == 0) {
        int base = (wvt * 64 + lane) * 21;
        #pragma unroll
        for (int cb = 0; cb < 4; ++cb)
            acc[cb] += *(const f32x4*)(red + base + cb * 4);
        float z = accz[0] + red[base + 16];
        float inv = 1.0f / z;
        float* ob = out + which * (2 * 64 * 4096) + b * (64 * 4096) + m;
        #pragma unroll
        for (int cb = 0; cb < 4; ++cb) {
            int c = cb * 16 + g * 4;
            #pragma unroll
            for (int r = 0; r < 4; ++r) ob[(c + r) * 4096] = acc[cb][r] * inv;
        }
    }
}

extern "C" void kernel_launch(void* const* d_in, const int* in_sizes, int n_in,
                              void* d_out, int out_size, void* d_ws, size_t ws_size,
                              hipStream_t stream) {
    const float* vi     = (const float*)d_in[0];
    const float* ir     = (const float*)d_in[1];
    const float* wsx_vi = (const float*)d_in[2];
    const float* wsy_vi = (const float*)d_in[3];
    const float* w1_vi  = (const float*)d_in[4];
    const float* wsx_q  = (const float*)d_in[6];
    const float* wsy_q  = (const float*)d_in[7];
    const float* w1_q   = (const float*)d_in[8];
    const float* b1_q   = (const float*)d_in[9];
    const float* wsx_ir = (const float*)d_in[10];
    const float* wsy_ir = (const float*)d_in[11];
    const float* w1_ir  = (const float*)d_in[12];
    const float* wv_vi  = (const float*)d_in[14];
    const float* bv_vi  = (const float*)d_in[15];
    const float* wv_ir  = (const float*)d_in[16];
    const float* bv_ir  = (const float*)d_in[17];
    (void)in_sizes; (void)n_in; (void)out_size;

    char* ws = (char*)d_ws;
    float* scal = (float*)ws;                              // 1088 B used
    float* e    = (float*)(ws + 1280);                     // 96 KB
    __hip_bfloat16* Vc = (__hip_bfloat16*)(ws + 99584);    // 2 MB
    float* out = (float*)d_out;
    (void)ws_size;

    kP_prep<<<dim3(320), 256, 0, stream>>>(vi, ir, wsx_vi, wsy_vi, wsx_q, wsy_q,
                                           wsx_ir, wsy_ir, w1_vi, w1_q, b1_q, w1_ir,
                                           wv_vi, bv_vi, wv_ir, bv_ir, e, scal, Vc);
    k4_attn<<<dim3(64, 4), 512, 0, stream>>>(e, scal, Vc, out);
}

// Round 9
// 34.458 us; speedup vs baseline: 2.3762x; 1.0137x over previous
//
#include <hip/hip_runtime.h>
#include <hip/hip_bf16.h>

typedef __attribute__((ext_vector_type(8))) short bf16x8;
typedef __attribute__((ext_vector_type(4))) float f32x4;
typedef __attribute__((ext_vector_type(4))) int   i32x4;

// ---------------------------------------------------------------------------
// B=2, C=64, H=W=64, N=4096, dk=8.
// Sobel weights are broadcast over [C,C,3,3] -> conv output = conv(chansum).
// Keys/queries affine in scalar field e[n]; softmax row m = softmax_n(t_m*e[n]),
// t_m = alpha*eq[m]+gamma; row max = t*e_max (t>0) else t*e_min.
// 2 graph nodes: kP (value GEMM + s byproduct + alpha/gamma) ->
//                k4 (sobel recompute per block + full-K attention).
// R6 lesson: no cross-block communication inside a node. s -> e sobel is
// recomputed per k4 block (deterministic, ~200 VALU ops/thread).
// R8 lesson: low-block-count tail kernels with strided 64-deep load loops
// (old chansum) serialize a whole node; fold reductions into GEMM loads.
// scal: [0..3] = alpha_vi, gamma_vi, alpha_ir, gamma_ir.
// s layout: [bm=b*2+mod][4096] channel sums.
// ---------------------------------------------------------------------------

// kP: blocks 0..255 value GEMM (V[c,n] = W x + b) + s byproduct;
//     block 256: alpha/gamma reduction.
__global__ __launch_bounds__(256) void kP_prep(
    const float* __restrict__ vi, const float* __restrict__ ir,
    const float* __restrict__ w1_vi, const float* __restrict__ w1_q,
    const float* __restrict__ b1_q,  const float* __restrict__ w1_ir,
    const float* __restrict__ wv_vi, const float* __restrict__ bv_vi,
    const float* __restrict__ wv_ir, const float* __restrict__ bv_ir,
    float* __restrict__ s, float* __restrict__ scal,
    __hip_bfloat16* __restrict__ Vc) {
    const int t = threadIdx.x;
    if (blockIdx.x < 256) {
        __shared__ __align__(16) char wlds[64 * 128];   // 64x64 bf16 swizzled
        const int bm = blockIdx.x >> 6, nt = blockIdx.x & 63;
        const int b = bm >> 1, mod = bm & 1;
        const float* wv = mod ? wv_ir : wv_vi;
        const float* bv = mod ? bv_ir : bv_vi;
        const float* x = (mod ? ir : vi) + b * (64 * 4096);
        {
            const float* src = wv + t * 16;
            int row = t >> 2, colb = (t & 3) * 32;
            int pk[8];
            #pragma unroll
            for (int j = 0; j < 8; ++j)
                asm("v_cvt_pk_bf16_f32 %0, %1, %2" : "=v"(pk[j])
                    : "v"(src[2 * j]), "v"(src[2 * j + 1]));
            int sw = (row & 7) << 4;
            i32x4 lo = {pk[0], pk[1], pk[2], pk[3]};
            i32x4 hi = {pk[4], pk[5], pk[6], pk[7]};
            *(i32x4*)(wlds + row * 128 + (colb ^ sw)) = lo;
            *(i32x4*)(wlds + row * 128 + ((colb + 16) ^ sw)) = hi;
        }
        __syncthreads();
        const int wvid = t >> 6, lane = t & 63;
        const int col = lane & 15, g = lane >> 4;
        const int n = nt * 64 + wvid * 16 + col;
        bf16x8 afr[4][2];
        #pragma unroll
        for (int cb = 0; cb < 4; ++cb) {
            int row = cb * 16 + col;
            int sw = (row & 7) << 4;
            #pragma unroll
            for (int ks = 0; ks < 2; ++ks)
                afr[cb][ks] = *(const bf16x8*)(wlds + row * 128 + ((ks * 64 + g * 16) ^ sw));
        }
        // B-frags from global, f32 -> bf16; accumulate channel sum as byproduct
        float ssum = 0.f;
        bf16x8 bfr[2];
        #pragma unroll
        for (int ks = 0; ks < 2; ++ks) {
            const float* xr = x + (ks * 32 + g * 8) * 4096 + n;
            float v[8];
            #pragma unroll
            for (int j = 0; j < 8; ++j) { v[j] = xr[j * 4096]; ssum += v[j]; }
            int pk[4];
            #pragma unroll
            for (int j = 0; j < 4; ++j)
                asm("v_cvt_pk_bf16_f32 %0, %1, %2" : "=v"(pk[j])
                    : "v"(v[2 * j]), "v"(v[2 * j + 1]));
            i32x4 bi = {pk[0], pk[1], pk[2], pk[3]};
            bfr[ks] = __builtin_bit_cast(bf16x8, bi);
        }
        // s[n] = sum over all 64 channels (4 g-groups hold 16 each)
        ssum += __shfl_xor(ssum, 16);
        ssum += __shfl_xor(ssum, 32);
        if (lane < 16) s[bm * 4096 + nt * 64 + wvid * 16 + lane] = ssum;

        f32x4 acc[4];
        #pragma unroll
        for (int cb = 0; cb < 4; ++cb)
            #pragma unroll
            for (int r = 0; r < 4; ++r) acc[cb][r] = bv[cb * 16 + g * 4 + r];
        #pragma unroll
        for (int ks = 0; ks < 2; ++ks)
            #pragma unroll
            for (int cb = 0; cb < 4; ++cb)
                acc[cb] = __builtin_amdgcn_mfma_f32_16x16x32_bf16(afr[cb][ks], bfr[ks], acc[cb], 0, 0, 0);
        __hip_bfloat16* outp = Vc + (size_t)(bm * 64) * 4096 + n;
        #pragma unroll
        for (int cb = 0; cb < 4; ++cb)
            #pragma unroll
            for (int r = 0; r < 4; ++r)
                outp[(cb * 16 + g * 4 + r) * 4096] = __float2bfloat16(acc[cb][r]);
    } else {
        // alpha/gamma: alpha = sum_d (sum_c w1_q[d,:]) * (sum_c w1_x[d,:]),
        // gamma = sum_d b1_q[d] * (sum_c w1_x[d,:])
        __shared__ float Ad[8], Cv[8], Ci[8], Bq[8];
        if (t < 8) {
            float a = 0.f;
            for (int c = 0; c < 128; ++c) a += w1_q[t * 128 + c];
            float cv = 0.f, ci = 0.f;
            for (int c = 0; c < 64; ++c) { cv += w1_vi[t * 64 + c]; ci += w1_ir[t * 64 + c]; }
            Ad[t] = a; Cv[t] = cv; Ci[t] = ci; Bq[t] = b1_q[t];
        }
        __syncthreads();
        if (t == 0) {
            float av = 0, gv = 0, ai = 0, gi = 0;
            for (int d = 0; d < 8; ++d) {
                av += Ad[d] * Cv[d]; gv += Bq[d] * Cv[d];
                ai += Ad[d] * Ci[d]; gi += Bq[d] * Ci[d];
            }
            scal[0] = av; scal[1] = gv; scal[2] = ai; scal[3] = gi;
        }
    }
}

// k4: per block: stage s (32 KB, via vbuf), compute e_att[4096] -> elds,
// e_q at own row, block-local min/max (identical across blocks) -> M.
// Then full-K attention: 8 K-chunks of 512, double-buffered V in LDS,
// 8 waves = (h: chunk K-half) x (wvt: 4 m-tiles). Final output direct.
#define CH 512
#define NCH 8
__global__ __launch_bounds__(512, 2) void k4_attn(
        const float* __restrict__ s, const float* __restrict__ scal,
        const float* __restrict__ wsx_vi, const float* __restrict__ wsy_vi,
        const float* __restrict__ wsx_q,  const float* __restrict__ wsy_q,
        const float* __restrict__ wsx_ir, const float* __restrict__ wsy_ir,
        const __hip_bfloat16* __restrict__ Vc, float* __restrict__ out) {
    __shared__ __align__(16) char vbuf[2][64 * CH * 2];  // 2 x 64 KB swizzled
    __shared__ __align__(16) float elds[4096];           // 16 KB e_att field
    __shared__ float mm[16];
    const int mt = blockIdx.x;    // spatial row (64 m-rows per block)
    const int bw = blockIdx.y;    // b*2+which
    const int b = bw >> 1, which = bw & 1;
    const int amod = which ? 0 : 1;
    const float* wsxa = amod ? wsx_ir : wsx_vi;
    const float* wsya = amod ? wsy_ir : wsy_vi;
    const float alpha = scal[which ? 0 : 2];
    const float gamma = scal[which ? 1 : 3];
    const short* Vg = (const short*)(Vc + (size_t)(bw * 64) * 4096);

    const int tid = threadIdx.x;
    const int wvw = tid >> 6, lane = tid & 63;
    const int h = wvw >> 2, wvt = wvw & 3;       // chunk K-half, m-tile
    const int col = lane & 15, g = lane >> 4;
    const int m = mt * 64 + wvt * 16 + col;

    // ---- phase A: stage s[b][2][4096] into vbuf (reused before V arrives) --
    float* sld = (float*)vbuf[0];
    const float* sg = s + (size_t)(b * 2) * 4096;
    #pragma unroll
    for (int k = 0; k < 16; ++k) { int i = tid + k * 512; sld[i] = sg[i]; }
    __syncthreads();

    // ---- phase B: e_att field + min/max; e_q at own m ----------------------
    float mn = 3.0e38f, mx = 0.f;
    {
        const float* sa = sld + amod * 4096;
        #pragma unroll
        for (int k2 = 0; k2 < 8; ++k2) {
            int n = tid + k2 * 512;
            int hh = n >> 6, ww = n & 63;
            float gx = 0.f, gy = 0.f;
            #pragma unroll
            for (int di = 0; di < 3; ++di)
                #pragma unroll
                for (int dj = 0; dj < 3; ++dj) {
                    int r = hh + di - 1, c2 = ww + dj - 1;
                    bool in = (r >= 0) & (r < 64) & (c2 >= 0) & (c2 < 64);
                    float v = in ? sa[r * 64 + c2] : 0.f;
                    int kk = di * 3 + dj;
                    gx = fmaf(v, wsxa[kk], gx);
                    gy = fmaf(v, wsya[kk], gy);
                }
            float ev = fabsf(gx) + fabsf(gy);
            elds[n] = ev;
            mn = fminf(mn, ev); mx = fmaxf(mx, ev);
        }
    }
    float eq;
    {
        int ww = wvt * 16 + col;
        float gx = 0.f, gy = 0.f;
        #pragma unroll
        for (int di = 0; di < 3; ++di)
            #pragma unroll
            for (int dj = 0; dj < 3; ++dj) {
                int r = mt + di - 1, c2 = ww + dj - 1;
                bool in = (r >= 0) & (r < 64) & (c2 >= 0) & (c2 < 64);
                float v = in ? (sld[r * 64 + c2] + sld[4096 + r * 64 + c2]) : 0.f;
                int kk = di * 3 + dj;
                gx = fmaf(v, wsx_q[kk], gx);
                gy = fmaf(v, wsy_q[kk], gy);
            }
        eq = fabsf(gx) + fabsf(gy);
    }
    #pragma unroll
    for (int o = 32; o; o >>= 1) {
        mn = fminf(mn, __shfl_xor(mn, o));
        mx = fmaxf(mx, __shfl_xor(mx, o));
    }
    if (lane == 0) { mm[wvw] = mn; mm[8 + wvw] = mx; }
    __syncthreads();             // also closes all sld reads
    float emn = mm[0], emx = mm[8];
    #pragma unroll
    for (int w = 1; w < 8; ++w) {
        emn = fminf(emn, mm[w]); emx = fmaxf(emx, mm[8 + w]);
    }
    const float L2E = 1.4426950408889634f;
    const float t  = alpha * eq + gamma;
    const float t2 = t * L2E;
    const float nM2 = -((t > 0.f) ? t * emx : t * emn) * L2E;

    // ---- phase C: stage V chunk 0 (overwrites sld) -------------------------
    #pragma unroll
    for (int k = 0; k < 8; ++k) {
        int id = tid + k * 512;
        int c = id >> 6, ss = id & 63;
        bf16x8 v = *(const bf16x8*)(Vg + c * 4096 + ss * 8);
        *(bf16x8*)(vbuf[0] + c * 1024 + ((ss * 16) ^ ((c & 31) << 4))) = v;
    }
    __syncthreads();

    f32x4 acc[4] = {};
    f32x4 accz = {};
    bf16x8 ones;
    #pragma unroll
    for (int j = 0; j < 8; ++j) ones[j] = (short)0x3F80;

    for (int ck = 0; ck < NCH; ++ck) {
        bf16x8 stg[8];
        const bool pf = (ck + 1 < NCH);
        if (pf) {
            const short* src = Vg + (ck + 1) * CH;
            #pragma unroll
            for (int k = 0; k < 8; ++k) {
                int id = tid + k * 512;
                int c = id >> 6, ss = id & 63;
                stg[k] = *(const bf16x8*)(src + c * 4096 + ss * 8);
            }
        }
        const char* vb = vbuf[ck & 1];
        const float* el = elds + ck * CH;
        #pragma unroll
        for (int it2 = 0; it2 < 8; ++it2) {
            const int n0 = (h * 8 + it2) * 32;
            bf16x8 af[4];
            #pragma unroll
            for (int cb = 0; cb < 4; ++cb) {
                int row = cb * 16 + col;
                int byte = row * 1024 + (((n0 + g * 8) * 2) ^ ((row & 31) << 4));
                af[cb] = *(const bf16x8*)(vb + byte);
            }
            f32x4 e0 = *(const f32x4*)(el + n0 + g * 8);
            f32x4 e1 = *(const f32x4*)(el + n0 + g * 8 + 4);
            float p[8];
            #pragma unroll
            for (int j = 0; j < 4; ++j) {
                float g0 = fmaf(e0[j], t2, nM2);
                float g1 = fmaf(e1[j], t2, nM2);
                asm("v_exp_f32 %0, %1" : "=v"(p[j])     : "v"(g0));
                asm("v_exp_f32 %0, %1" : "=v"(p[j + 4]) : "v"(g1));
            }
            int pk0, pk1, pk2, pk3;
            asm("v_cvt_pk_bf16_f32 %0, %1, %2" : "=v"(pk0) : "v"(p[0]), "v"(p[1]));
            asm("v_cvt_pk_bf16_f32 %0, %1, %2" : "=v"(pk1) : "v"(p[2]), "v"(p[3]));
            asm("v_cvt_pk_bf16_f32 %0, %1, %2" : "=v"(pk2) : "v"(p[4]), "v"(p[5]));
            asm("v_cvt_pk_bf16_f32 %0, %1, %2" : "=v"(pk3) : "v"(p[6]), "v"(p[7]));
            i32x4 pki = {pk0, pk1, pk2, pk3};
            bf16x8 bfrag = __builtin_bit_cast(bf16x8, pki);
            #pragma unroll
            for (int cb = 0; cb < 4; ++cb)
                acc[cb] = __builtin_amdgcn_mfma_f32_16x16x32_bf16(af[cb], bfrag, acc[cb], 0, 0, 0);
            accz = __builtin_amdgcn_mfma_f32_16x16x32_bf16(ones, bfrag, accz, 0, 0, 0);
        }
        __syncthreads();
        if (pf) {
            char* wb = vbuf[(ck + 1) & 1];
            #pragma unroll
            for (int k = 0; k < 8; ++k) {
                int id = tid + k * 512;
                int c = id >> 6, ss = id & 63;
                *(bf16x8*)(wb + c * 1024 + ((ss * 16) ^ ((c & 31) << 4))) = stg[k];
            }
            __syncthreads();
        }
    }

    // combine chunk-halves through LDS, normalize, write final output
    float* red = (float*)vbuf[0];
    if (h == 1) {
        int base = (wvt * 64 + lane) * 21;
        #pragma unroll
        for (int cb = 0; cb < 4; ++cb)
            *(f32x4*)(red + base + cb * 4) = acc[cb];
        red[base + 16] = accz[0];
    }
    __syncthreads();
    if (h == 0) {
        int base = (wvt * 64 + lane) * 21;
        #pragma unroll
        for (int cb = 0; cb < 4; ++cb)
            acc[cb] += *(const f32x4*)(red + base + cb * 4);
        float z = accz[0] + red[base + 16];
        float inv = 1.0f / z;
        float* ob = out + which * (2 * 64 * 4096) + b * (64 * 4096) + m;
        #pragma unroll
        for (int cb = 0; cb < 4; ++cb) {
            int c = cb * 16 + g * 4;
            #pragma unroll
            for (int r = 0; r < 4; ++r) ob[(c + r) * 4096] = acc[cb][r] * inv;
        }
    }
}

extern "C" void kernel_launch(void* const* d_in, const int* in_sizes, int n_in,
                              void* d_out, int out_size, void* d_ws, size_t ws_size,
                              hipStream_t stream) {
    const float* vi     = (const float*)d_in[0];
    const float* ir     = (const float*)d_in[1];
    const float* wsx_vi = (const float*)d_in[2];
    const float* wsy_vi = (const float*)d_in[3];
    const float* w1_vi  = (const float*)d_in[4];
    const float* wsx_q  = (const float*)d_in[6];
    const float* wsy_q  = (const float*)d_in[7];
    const float* w1_q   = (const float*)d_in[8];
    const float* b1_q   = (const float*)d_in[9];
    const float* wsx_ir = (const float*)d_in[10];
    const float* wsy_ir = (const float*)d_in[11];
    const float* w1_ir  = (const float*)d_in[12];
    const float* wv_vi  = (const float*)d_in[14];
    const float* bv_vi  = (const float*)d_in[15];
    const float* wv_ir  = (const float*)d_in[16];
    const float* bv_ir  = (const float*)d_in[17];
    (void)in_sizes; (void)n_in; (void)out_size;

    char* ws = (char*)d_ws;
    float* scal = (float*)ws;                              // 64 B used
    float* s    = (float*)(ws + 1280);                     // 64 KB [4][4096]
    __hip_bfloat16* Vc = (__hip_bfloat16*)(ws + 1280 + 65536);  // 2 MB
    float* out = (float*)d_out;
    (void)ws_size;

    kP_prep<<<dim3(257), 256, 0, stream>>>(vi, ir, w1_vi, w1_q, b1_q, w1_ir,
                                           wv_vi, bv_vi, wv_ir, bv_ir, s, scal, Vc);
    k4_attn<<<dim3(64, 4), 512, 0, stream>>>(s, scal, wsx_vi, wsy_vi, wsx_q, wsy_q,
                                             wsx_ir, wsy_ir, Vc, out);
}